// Round 1
// baseline (2640.207 us; speedup 1.0000x reference)
//
#include <hip/hip_runtime.h>
#include <hip/hip_bf16.h>
#include <math.h>

#define N_IMG 4
#define CIN 512
#define NANCH 36864          // 64*64*9
#define PRE_NMS_N 3000
#define POST_NMS_N 300
#define NWORD 47             // ceil(3000/64)

// out layout (floats)
#define OFF_SCORES 589824
#define OFF_ROIS   884736
#define OFF_VALID  889536
#define OFF_ANCH   890736

// ---------------- K1: 3x3 conv 512->512 + bias + ReLU ----------------
__global__ __launch_bounds__(256) void k1_conv3x3(
    const float* __restrict__ x, const float* __restrict__ W1,
    const float* __restrict__ b1, float* __restrict__ h) {
  const int n = blockIdx.z, y = blockIdx.y, cog = blockIdx.x;
  const int tid = threadIdx.x;
  __shared__ __align__(16) float xs[8][3][68];
  __shared__ __align__(16) float wsm[72][64];
  const int px0 = (tid & 15) * 4;
  const int col0 = (tid >> 4) * 4;
  float acc[4][4] = {{0.f}};
  const float* xn = x + (size_t)n * CIN * 4096;
  for (int cc = 0; cc < 64; ++cc) {
    const int ci0 = cc * 8;
    __syncthreads();
    for (int idx = tid; idx < 8 * 3 * 68; idx += 256) {
      int ci = idx / 204, rem = idx - ci * 204;
      int r = rem / 68, c = rem - r * 68;
      int col = c - 1, row = y + r - 1;
      float v = 0.f;
      if (c < 66 && col >= 0 && col < 64 && row >= 0 && row < 64)
        v = xn[(size_t)(ci0 + ci) * 4096 + row * 64 + col];
      xs[ci][r][c] = v;
    }
    for (int g = tid; g < 512; g += 256) {
      int co_l = g >> 3, ci = g & 7;
      const float* wp = W1 + (size_t)(cog * 64 + co_l) * 4608 + (ci0 + ci) * 9;
      #pragma unroll
      for (int kk = 0; kk < 9; ++kk) wsm[ci * 9 + kk][co_l] = wp[kk];
    }
    __syncthreads();
    #pragma unroll
    for (int ci = 0; ci < 8; ++ci) {
      #pragma unroll
      for (int ky = 0; ky < 3; ++ky) {
        float xv[6];
        #pragma unroll
        for (int u = 0; u < 6; ++u) xv[u] = xs[ci][ky][px0 + u];
        #pragma unroll
        for (int kx = 0; kx < 3; ++kx) {
          const float* wr = &wsm[ci * 9 + ky * 3 + kx][col0];
          float w0 = wr[0], w1 = wr[1], w2 = wr[2], w3 = wr[3];
          #pragma unroll
          for (int p = 0; p < 4; ++p) {
            float xe = xv[kx + p];
            acc[0][p] = fmaf(w0, xe, acc[0][p]);
            acc[1][p] = fmaf(w1, xe, acc[1][p]);
            acc[2][p] = fmaf(w2, xe, acc[2][p]);
            acc[3][p] = fmaf(w3, xe, acc[3][p]);
          }
        }
      }
    }
  }
  #pragma unroll
  for (int c = 0; c < 4; ++c) {
    int co = cog * 64 + col0 + c;
    float bias = b1[co];
    float4 o;
    o.x = fmaxf(acc[c][0] + bias, 0.f);
    o.y = fmaxf(acc[c][1] + bias, 0.f);
    o.z = fmaxf(acc[c][2] + bias, 0.f);
    o.w = fmaxf(acc[c][3] + bias, 0.f);
    *(float4*)(h + (size_t)(n * CIN + co) * 4096 + y * 64 + px0) = o;
  }
}

// ---------------- K2: 1x1 heads + softmax-fg ----------------
__global__ __launch_bounds__(256) void k2_heads(
    const float* __restrict__ h,
    const float* __restrict__ Wl, const float* __restrict__ bl,
    const float* __restrict__ Ws, const float* __restrict__ bs,
    float* __restrict__ rpn_locs, float* __restrict__ rpn_scores,
    float* __restrict__ fg) {
  const int y = blockIdx.x, n = blockIdx.y;
  const int tid = threadIdx.x;
  const int px = tid & 63, cg = tid >> 6;
  const int base = cg * 14;
  const int cntc = (cg == 3) ? 12 : 14;
  __shared__ float hs[32][64];
  __shared__ float wsm[54][32];
  float acc[14];
  #pragma unroll
  for (int c = 0; c < 14; ++c) acc[c] = 0.f;
  const float* hn = h + (size_t)n * CIN * 4096 + y * 64;
  for (int k0 = 0; k0 < 512; k0 += 32) {
    __syncthreads();
    for (int idx = tid; idx < 32 * 64; idx += 256) {
      int k = idx >> 6, p = idx & 63;
      hs[k][p] = hn[(size_t)(k0 + k) * 4096 + p];
    }
    for (int idx = tid; idx < 54 * 32; idx += 256) {
      int ch = idx >> 5, k = idx & 31;
      wsm[ch][k] = (ch < 36) ? Wl[ch * 512 + k0 + k] : Ws[(ch - 36) * 512 + k0 + k];
    }
    __syncthreads();
    for (int k = 0; k < 32; ++k) {
      float xv = hs[k][px];
      #pragma unroll
      for (int c = 0; c < 14; ++c)
        if (c < cntc) acc[c] = fmaf(wsm[base + c][k], xv, acc[c]);
    }
  }
  const int p = y * 64 + px;
  const size_t pbase = (size_t)n * NANCH + (size_t)p * 9;
  for (int c = 0; c < cntc; ++c) {
    int ch = base + c;
    if (ch < 36) {
      float v = acc[c] + bl[ch];
      rpn_locs[(pbase + (ch >> 2)) * 4 + (ch & 3)] = v;
    } else {
      int sc = ch - 36;
      float v = acc[c] + bs[sc];
      rpn_scores[(pbase + (sc >> 1)) * 2 + (sc & 1)] = v;
    }
  }
  if (cg >= 2) {
    int sstart = (base >= 36) ? base : 36;
    for (int ch = sstart; ch + 1 <= base + cntc - 1; ch += 2) {
      float s0 = acc[ch - base] + bs[ch - 36];
      float s1 = acc[ch + 1 - base] + bs[ch + 1 - 36];
      float m = fmaxf(s0, s1);
      float e0 = expf(s0 - m), e1 = expf(s1 - m);
      fg[(size_t)n * NANCH + (size_t)p * 9 + ((ch - 36) >> 1)] = e1 / (e0 + e1);
    }
  }
}

// ---------------- K3: anchors + decode + clip + key ----------------
__global__ void k3_decode(
    const float* __restrict__ locs, const float* __restrict__ fg,
    const int* __restrict__ ihp, const int* __restrict__ iwp,
    float* __restrict__ anchors_out, float4* __restrict__ boxes,
    unsigned long long* __restrict__ keys) {
  int gid = blockIdx.x * 256 + threadIdx.x;
  if (gid >= N_IMG * NANCH) return;
  int n = gid / NANCH, i = gid - n * NANCH;
  int p = i / 9, a = i - p * 9;
  int yy = p >> 6, xx = p & 63;
  int ri = a / 3, si = a - ri * 3;
  const float ratios[3] = {0.5f, 1.0f, 2.0f};
  const float scales[3] = {8.f, 16.f, 32.f};
  float hh = 16.f * scales[si] * sqrtf(ratios[ri]);
  float ww = 16.f * scales[si] * sqrtf(1.0f / ratios[ri]);
  float by1 = 8.f - hh * 0.5f, bx1 = 8.f - ww * 0.5f;
  float by2 = 8.f + hh * 0.5f, bx2 = 8.f + ww * 0.5f;
  float ay1 = yy * 16.f + by1, ax1 = xx * 16.f + bx1;
  float ay2 = yy * 16.f + by2, ax2 = xx * 16.f + bx2;
  if (n == 0) {
    float* ao = anchors_out + (size_t)i * 4;
    ao[0] = ay1; ao[1] = ax1; ao[2] = ay2; ao[3] = ax2;
  }
  const float* lp = locs + ((size_t)n * NANCH + i) * 4;
  float dy = lp[0], dx = lp[1], dh = lp[2], dw = lp[3];
  float ah = ay2 - ay1, aw = ax2 - ax1;
  float acy = ay1 + 0.5f * ah, acx = ax1 + 0.5f * aw;
  float cy = dy * ah + acy, cx = dx * aw + acx;
  float hb = expf(dh) * ah, wb = expf(dw) * aw;
  float imh = (float)ihp[0], imw = (float)iwp[0];
  float y1 = fminf(fmaxf(cy - 0.5f * hb, 0.f), imh);
  float x1 = fminf(fmaxf(cx - 0.5f * wb, 0.f), imw);
  float y2 = fminf(fmaxf(cy + 0.5f * hb, 0.f), imh);
  float x2 = fminf(fmaxf(cx + 0.5f * wb, 0.f), imw);
  bool valid = ((y2 - y1) >= 16.0f) && ((x2 - x1) >= 16.0f);
  float s = valid ? fg[(size_t)n * NANCH + i] : -__builtin_inff();
  boxes[(size_t)n * NANCH + i] = make_float4(y1, x1, y2, x2);
  unsigned int fb = __float_as_uint(s);
  unsigned int mono = (fb & 0x80000000u) ? ~fb : (fb | 0x80000000u);
  keys[(size_t)n * NANCH + i] =
      (((unsigned long long)mono) << 32) | (unsigned int)(~(unsigned int)i);
}

// ---------------- K4: per-image exact top-3000 (sorted desc) ----------------
__global__ __launch_bounds__(1024) void k4_select(
    const unsigned long long* __restrict__ keys, const float4* __restrict__ boxes,
    float4* __restrict__ sboxes, unsigned int* __restrict__ sfin) {
  const int n = blockIdx.x, tid = threadIdx.x;
  const unsigned long long* kk = keys + (size_t)n * NANCH;
  __shared__ unsigned int hist[2048];
  __shared__ unsigned int suf[2048];
  __shared__ unsigned long long sb[4096];
  __shared__ int selb;
  __shared__ unsigned int cnt;
  unsigned long long prefix = 0ull;
  int need = PRE_NMS_N;
  const int shifts[6] = {53, 42, 31, 20, 10, 0};
  const int widths[6] = {11, 11, 11, 11, 10, 10};
  for (int rd = 0; rd < 6; ++rd) {
    const int s = shifts[rd], w = widths[rd];
    const int hib = s + w;
    for (int b = tid; b < 2048; b += 1024) hist[b] = 0u;
    __syncthreads();
    for (int i = tid; i < NANCH; i += 1024) {
      unsigned long long key = kk[i];
      bool match = (hib >= 64) || (((key ^ prefix) >> hib) == 0ull);
      if (match)
        atomicAdd(&hist[(unsigned)((key >> s) & ((1u << w) - 1u))], 1u);
    }
    __syncthreads();
    for (int off = 1; off < 2048; off <<= 1) {
      for (int b = tid; b < 2048; b += 1024)
        suf[b] = hist[b] + ((b + off < 2048) ? hist[b + off] : 0u);
      __syncthreads();
      for (int b = tid; b < 2048; b += 1024) hist[b] = suf[b];
      __syncthreads();
    }
    const int nb = 1 << w;
    for (int b = tid; b < nb; b += 1024) {
      unsigned int sv = hist[b];
      unsigned int nxt = (b + 1 < 2048) ? hist[b + 1] : 0u;
      if (sv >= (unsigned)need && nxt < (unsigned)need) selb = b;
    }
    __syncthreads();
    int bstar = selb;
    unsigned int cgt = (bstar + 1 < 2048) ? hist[bstar + 1] : 0u;
    need -= (int)cgt;
    prefix |= ((unsigned long long)bstar) << s;
    __syncthreads();
  }
  if (tid == 0) cnt = 0u;
  __syncthreads();
  for (int i = tid; i < NANCH; i += 1024) {
    unsigned long long key = kk[i];
    if (key >= prefix) {
      unsigned int pos = atomicAdd(&cnt, 1u);
      if (pos < 4096u) sb[pos] = ~key;   // inverted -> ascending sort = desc keys
    }
  }
  __syncthreads();
  unsigned int c0 = cnt;
  for (int i = tid; i < 4096; i += 1024)
    if (i >= (int)c0) sb[i] = 0xFFFFFFFFFFFFFFFFull;
  __syncthreads();
  for (int k2 = 2; k2 <= 4096; k2 <<= 1) {
    for (int j = k2 >> 1; j > 0; j >>= 1) {
      for (int t = tid; t < 2048; t += 1024) {
        int i = ((t & ~(j - 1)) << 1) | (t & (j - 1));
        int pp = i + j;
        bool up = ((i & k2) == 0);
        unsigned long long va = sb[i], vb = sb[pp];
        bool sw = up ? (va > vb) : (va < vb);
        if (sw) { sb[i] = vb; sb[pp] = va; }
      }
      __syncthreads();
    }
  }
  const float4* bx = boxes + (size_t)n * NANCH;
  for (int r = tid; r < PRE_NMS_N; r += 1024) {
    unsigned long long key = ~sb[r];
    unsigned int idx = ~((unsigned int)(key & 0xFFFFFFFFull));
    sboxes[(size_t)n * PRE_NMS_N + r] = bx[idx];
    unsigned int hi32 = (unsigned int)(key >> 32);
    sfin[n * PRE_NMS_N + r] = (hi32 > 0x007FFFFFu) ? 1u : 0u;  // > mono(-inf)
  }
}

// ---------------- K5: suppression bitmask ----------------
__global__ __launch_bounds__(256) void k5_mask(
    const float4* __restrict__ sboxes, unsigned long long* __restrict__ mask) {
  const int chunk = blockIdx.x, n = blockIdx.y;
  __shared__ float4 bs[PRE_NMS_N];
  for (int i = threadIdx.x; i < PRE_NMS_N; i += 256)
    bs[i] = sboxes[(size_t)n * PRE_NMS_N + i];
  __syncthreads();
  for (int w = threadIdx.x; w < 64 * NWORD; w += 256) {
    int il = w / NWORD, wd = w - il * NWORD;
    int i = chunk * 64 + il;
    if (i >= PRE_NMS_N) continue;
    float4 bi = bs[i];
    float areai = (bi.z - bi.x) * (bi.w - bi.y);
    unsigned long long bits = 0ull;
    int j0 = wd * 64;
    #pragma unroll 4
    for (int t = 0; t < 64; ++t) {
      int j = j0 + t;
      if (j >= PRE_NMS_N) break;
      float4 bj = bs[j];
      float y1 = fmaxf(bi.x, bj.x), x1 = fmaxf(bi.y, bj.y);
      float y2 = fminf(bi.z, bj.z), x2 = fminf(bi.w, bj.w);
      float inter = fmaxf(y2 - y1, 0.f) * fmaxf(x2 - x1, 0.f);
      float areaj = (bj.z - bj.x) * (bj.w - bj.y);
      float uni = areai + areaj - inter;
      float iou = (uni > 0.f) ? inter / uni : 0.f;
      if (iou > 0.7f) bits |= (1ull << t);
    }
    mask[((size_t)n * PRE_NMS_N + i) * NWORD + wd] = bits;
  }
}

// ---------------- K6: sequential greedy NMS + outputs (1 wave/image) ----------------
__global__ __launch_bounds__(64) void k6_nms(
    const unsigned long long* __restrict__ mask, const float4* __restrict__ sboxes,
    const unsigned int* __restrict__ sfin,
    float* __restrict__ out_rois, float* __restrict__ out_valid) {
  const int n = blockIdx.x, lane = threadIdx.x;
  const unsigned long long* M = mask + (size_t)n * PRE_NMS_N * NWORD;
  __shared__ int keepS[PRE_NMS_N];
  unsigned long long R = 0ull;
  unsigned long long row = (lane < NWORD) ? M[lane] : 0ull;
  for (int i = 0; i < PRE_NMS_N; ++i) {
    unsigned long long nxt =
        (lane < NWORD && i + 1 < PRE_NMS_N) ? M[(size_t)(i + 1) * NWORD + lane] : 0ull;
    int w = i >> 6, b = i & 63;
    unsigned int rlo = (unsigned int)R, rhi = (unsigned int)(R >> 32);
    rlo = (unsigned int)__shfl((int)rlo, w, 64);
    rhi = (unsigned int)__shfl((int)rhi, w, 64);
    unsigned long long Rw = (((unsigned long long)rhi) << 32) | rlo;
    int kept = !((Rw >> b) & 1ull);
    if (kept && lane < NWORD) R |= row;
    if (lane == 0) keepS[i] = kept;
    row = nxt;
  }
  __syncthreads();
  const unsigned int* fin = sfin + n * PRE_NMS_N;
  int running = 0;
  for (int c = 0; c < NWORD; ++c) {
    int i = c * 64 + lane;
    int kf = (i < PRE_NMS_N) ? (keepS[i] && fin[i]) : 0;
    unsigned long long m = __ballot(kf);
    if (kf) {
      int r = running + __popcll(m & ((1ull << lane) - 1ull));
      if (r < POST_NMS_N) {
        float4 b4 = sboxes[(size_t)n * PRE_NMS_N + i];
        float* o = out_rois + (size_t)(n * POST_NMS_N + r) * 4;
        o[0] = b4.x; o[1] = b4.y; o[2] = b4.z; o[3] = b4.w;
        out_valid[n * POST_NMS_N + r] = 1.0f;
      }
    }
    running += __popcll(m);
  }
  int keptTotal = running;
  if (keptTotal < POST_NMS_N) {
    int runN = 0;
    for (int c = 0; c < NWORD && keptTotal + runN < POST_NMS_N; ++c) {
      int i = c * 64 + lane;
      int nf = (i < PRE_NMS_N) ? !(keepS[i] && fin[i]) : 0;
      unsigned long long m = __ballot(nf);
      if (nf) {
        int r = keptTotal + runN + __popcll(m & ((1ull << lane) - 1ull));
        if (r < POST_NMS_N) {
          float* o = out_rois + (size_t)(n * POST_NMS_N + r) * 4;
          o[0] = 0.f; o[1] = 0.f; o[2] = 0.f; o[3] = 0.f;
          out_valid[n * POST_NMS_N + r] = 0.0f;
        }
      }
      runN += __popcll(m);
    }
  }
}

extern "C" void kernel_launch(void* const* d_in, const int* in_sizes, int n_in,
                              void* d_out, int out_size, void* d_ws, size_t ws_size,
                              hipStream_t stream) {
  const float* x  = (const float*)d_in[0];
  const float* W1 = (const float*)d_in[1];
  const float* b1 = (const float*)d_in[2];
  const float* Ws = (const float*)d_in[3];
  const float* bs = (const float*)d_in[4];
  const float* Wl = (const float*)d_in[5];
  const float* bl = (const float*)d_in[6];
  const int* ihp  = (const int*)d_in[7];
  const int* iwp  = (const int*)d_in[8];

  float* out = (float*)d_out;
  float* o_locs   = out;
  float* o_scores = out + OFF_SCORES;
  float* o_rois   = out + OFF_ROIS;
  float* o_valid  = out + OFF_VALID;
  float* o_anch   = out + OFF_ANCH;

  char* ws = (char*)d_ws;
  float* h                    = (float*)ws;                       // 33,554,432 B
  float* fg                   = (float*)(ws + 33554432);          //    589,824 B
  float4* boxes               = (float4*)(ws + 34144256);         //  2,359,296 B
  unsigned long long* keys    = (unsigned long long*)(ws + 36503552); // 1,179,648 B
  float4* sboxes              = (float4*)(ws + 37683200);         //    192,000 B
  unsigned int* sfin          = (unsigned int*)(ws + 37875200);   //     48,000 B
  unsigned long long* mask    = (unsigned long long*)ws;          // reuse h region (4.5 MB), h dead after K2

  k1_conv3x3<<<dim3(8, 64, 4), 256, 0, stream>>>(x, W1, b1, h);
  k2_heads<<<dim3(64, 4), 256, 0, stream>>>(h, Wl, bl, Ws, bs, o_locs, o_scores, fg);
  k3_decode<<<(N_IMG * NANCH + 255) / 256, 256, 0, stream>>>(o_locs, fg, ihp, iwp,
                                                             o_anch, boxes, keys);
  k4_select<<<4, 1024, 0, stream>>>(keys, boxes, sboxes, sfin);
  k5_mask<<<dim3(NWORD, 4), 256, 0, stream>>>(sboxes, mask);
  k6_nms<<<4, 64, 0, stream>>>(mask, sboxes, sfin, o_rois, o_valid);
}